// Round 8
// baseline (462.935 us; speedup 1.0000x reference)
//
#include <hip/hip_runtime.h>
#include <hip/hip_bf16.h>
#include <cstdio>
#include <cstdint>

// GAT_37580963840365: 2-layer TransformerConv (H=4, C=32, HC=128) + MLP head.
// Softmax WITHOUT max-subtraction (shift-invariant, exp2-domain, clamp 2^72)
// -> all edge weights independent. Layer 0 collapsed to bilinear form
// (G = 3x4/head) with fused scalar-agg + expand (LDS handoff). Layer 1:
// LDS-staged MFMA GEMM -> KV interleaved rows; agg1 = round-6 geometry
// (32 lanes/edge, 4 edges in flight) in 256-thr blocks for occupancy.
// Classifier fused with LDS-staged weights. 8 dispatches total.

typedef short s16x8 __attribute__((ext_vector_type(8)));
typedef float f32x4 __attribute__((ext_vector_type(4)));

static inline int cdiv(int a, int b) { return (a + b - 1) / b; }

#define EXP2F(x) __builtin_amdgcn_exp2f(x)
#define LOG2E 1.4426950408889634f
#define RSC 0.17677669529663687f  // 1/sqrt(32)

__device__ __forceinline__ float bflo(unsigned u) {
    union { unsigned i; float f; } x; x.i = u << 16; return x.f;
}
__device__ __forceinline__ float bfhi(unsigned u) {
    union { unsigned i; float f; } x; x.i = u & 0xffff0000u; return x.f;
}
__device__ __forceinline__ unsigned short f2b(float f) {
    __hip_bfloat16 h = __float2bfloat16(f);
    return *reinterpret_cast<unsigned short*>(&h);
}
__device__ __forceinline__ unsigned packbf(float lo, float hi) {
    return (unsigned)f2b(lo) | ((unsigned)f2b(hi) << 16);
}

// ---------------- hist + weight pack + layer-0 bilinear coefs (one dispatch) --

__global__ __launch_bounds__(256) void histpack_kernel(
    const int* __restrict__ dst, int E, int* __restrict__ counts, int nb_hist,
    const float* __restrict__ Wq1, const float* __restrict__ Wk1,
    const float* __restrict__ Wv1, const float* __restrict__ Ws1,
    const float* __restrict__ Wc1, const float* __restrict__ Wc2,
    unsigned short* __restrict__ wpk,
    const float* __restrict__ Wq0, const float* __restrict__ bq0,
    const float* __restrict__ Wk0, const float* __restrict__ bk0,
    const float* __restrict__ We0, float* __restrict__ gcoef) {
    int bid = blockIdx.x;
    if (bid < nb_hist) {  // histogram part
        int e = bid * 256 + threadIdx.x;
        if (e < E) atomicAdd(&counts[dst[e]], 1);
        return;
    }
    int pb = bid - nb_hist;
    if (pb == 352) {  // gcoef: G[h][i][j] = rsc*log2e * dot32(A_i, B_j)
        int t = threadIdx.x;
        if (t < 48) {
            int h = t / 12, r = t % 12, i = r >> 2, j = r & 3;
            const float* A = (i == 0) ? Wq0 : (i == 1) ? (Wq0 + 128) : bq0;
            const float* B = (j == 0) ? Wk0 : (j == 1) ? (Wk0 + 128) : (j == 2) ? We0 : bk0;
            float s = 0.f;
            for (int c = 0; c < 32; ++c) s += A[h * 32 + c] * B[h * 32 + c];
            gcoef[h * 12 + i * 4 + j] = s * (RSC * LOG2E);
        }
        return;
    }
    // pack: wpk[((kc*CT+ct)*64+lane)*8+j] = bf16(W[kc*32+(lane>>4)*8+j][ct*16+(lane&15)])
    int idx = pb * 256 + threadIdx.x;
    int local, COLS;
    const float* W;
    if (idx < 81920) {
        int m = idx >> 14;
        local = idx & 16383;
        COLS = 128;
        W = (m == 0) ? Wq1 : (m == 1) ? Wk1 : (m == 2) ? Wv1 : (m == 3) ? Ws1 : Wc1;
    } else {
        local = idx - 81920;
        COLS = 64;
        W = Wc2;
    }
    int CT = COLS >> 4;
    int j = local & 7, lane = (local >> 3) & 63, t = local >> 9;
    int ct = t % CT, kc = t / CT;
    int k = kc * 32 + ((lane >> 4) << 3) + j;
    int nn = (ct << 4) + (lane & 15);
    wpk[idx] = f2b(W[k * COLS + nn]);
}

// ---------------- single-block exclusive scan over counts -> offsets ---------

__global__ __launch_bounds__(1024) void scan1_kernel(const int* __restrict__ counts,
                                                     int n, int* __restrict__ offsets) {
    __shared__ int ts[1024];
    const int CH = 100;
    int t = threadIdx.x;
    int base = t * CH;
    int endi = min(base + CH, n);
    int s = 0;
    int i = base;
    for (; i + 3 < endi; i += 4) {
        int4 v = *(const int4*)(counts + i);
        s += v.x + v.y + v.z + v.w;
    }
    for (; i < endi; ++i) s += counts[i];
    ts[t] = s;
    __syncthreads();
    for (int off = 1; off < 1024; off <<= 1) {
        int x = (t >= off) ? ts[t - off] : 0;
        __syncthreads();
        ts[t] += x;
        __syncthreads();
    }
    if (t == 1023) offsets[n] = ts[1023];
    int excl = ts[t] - s;
    for (int k = base; k < endi; ++k) {
        int c = counts[k];
        offsets[k] = excl;
        excl += c;
    }
}

// scatter: consumes counts via atomicSub; packs {src*512, ea_bits} into int2.
__global__ __launch_bounds__(256) void scatter_kernel(const int* __restrict__ src,
                                                      const int* __restrict__ dst,
                                                      const float* __restrict__ ea, int E,
                                                      const int* __restrict__ offsets,
                                                      int* __restrict__ counts,
                                                      int2* __restrict__ csr) {
    int e = blockIdx.x * 256 + threadIdx.x;
    if (e >= E) return;
    int d = dst[e];
    int r = atomicSub(&counts[d], 1);
    int p = offsets[d] + r - 1;
    csr[p] = make_int2(src[e] << 9, __float_as_int(ea[e]));
}

// ---------------- layer 0: fused scalar-agg + expand ----------------
// Phase 1: thread = (node, head); accumulate (Sw*xs0, Sw*xs1, Sw*ea, Sw) -> LDS.
// Phase 2: thread = (node, 4-ch group); reconstruct 128-ch bf16 row from LDS.

__global__ __launch_bounds__(256) void agg0x_kernel(
    const float* __restrict__ x, const float* __restrict__ gcoef,
    const float* __restrict__ Wv, const float* __restrict__ bv,
    const float* __restrict__ We, const float* __restrict__ Ws,
    const float* __restrict__ bs, uint2* __restrict__ H0,
    const int* __restrict__ offsets, const int2* __restrict__ csr, int n_nodes) {
    __shared__ float4 sm[256];  // [64 nodes][4 heads]
    int t = threadIdx.x;
    int nb = blockIdx.x * 64;
    {
        int n = nb + (t >> 2), h = t & 3;
        if (n < n_nodes) {
            float2 xn = ((const float2*)x)[n];
            const float4* G4 = (const float4*)gcoef;
            float4 g0 = G4[h * 3 + 0], g1 = G4[h * 3 + 1], g2 = G4[h * 3 + 2];
            float c0 = fmaf(xn.y, g1.x, fmaf(xn.x, g0.x, g2.x));
            float c1 = fmaf(xn.y, g1.y, fmaf(xn.x, g0.y, g2.y));
            float c2 = fmaf(xn.y, g1.z, fmaf(xn.x, g0.z, g2.z));
            float c3 = fmaf(xn.y, g1.w, fmaf(xn.x, g0.w, g2.w));
            int beg = offsets[n], end = offsets[n + 1];
            float d = 0.f, X0 = 0.f, X1 = 0.f, EA = 0.f;
            for (int j = beg; j < end; ++j) {
                int2 ce = csr[j];
                float e = __int_as_float(ce.y);
                float2 xs = *(const float2*)((const char*)x + (((unsigned)ce.x) >> 6));
                float al = fmaf(c0, xs.x, fmaf(c1, xs.y, fmaf(c2, e, c3)));
                float w = EXP2F(fminf(al, 72.f));
                d += w;
                X0 = fmaf(w, xs.x, X0);
                X1 = fmaf(w, xs.y, X1);
                EA = fmaf(w, e, EA);
            }
            sm[t] = make_float4(X0, X1, EA, d);
        }
    }
    __syncthreads();
    int g = t & 31;  // 4-channel group, constant per thread across iterations
    float4 wv0 = ((const float4*)Wv)[g], wv1 = ((const float4*)(Wv + 128))[g];
    float4 we = ((const float4*)We)[g], bv4 = ((const float4*)bv)[g];
    float4 ws0 = ((const float4*)Ws)[g], ws1 = ((const float4*)(Ws + 128))[g];
    float4 bs4 = ((const float4*)bs)[g];
    int h = g >> 3;
#pragma unroll
    for (int it = 0; it < 8; ++it) {
        int ln = it * 8 + (t >> 5);
        int n2 = nb + ln;
        if (n2 >= n_nodes) break;
        float4 ag = sm[ln * 4 + h];
        float inv = 1.f / (ag.w + 1e-16f);
        float2 xn = ((const float2*)x)[n2];
        float o0 = fmaf(wv0.x, ag.x, fmaf(wv1.x, ag.y, fmaf(we.x, ag.z, bv4.x * ag.w))) * inv
                 + fmaf(xn.x, ws0.x, fmaf(xn.y, ws1.x, bs4.x));
        float o1 = fmaf(wv0.y, ag.x, fmaf(wv1.y, ag.y, fmaf(we.y, ag.z, bv4.y * ag.w))) * inv
                 + fmaf(xn.x, ws0.y, fmaf(xn.y, ws1.y, bs4.y));
        float o2 = fmaf(wv0.z, ag.x, fmaf(wv1.z, ag.y, fmaf(we.z, ag.z, bv4.z * ag.w))) * inv
                 + fmaf(xn.x, ws0.z, fmaf(xn.y, ws1.z, bs4.z));
        float o3 = fmaf(wv0.w, ag.x, fmaf(wv1.w, ag.y, fmaf(we.w, ag.z, bv4.w * ag.w))) * inv
                 + fmaf(xn.x, ws0.w, fmaf(xn.y, ws1.w, bs4.w));
        uint2 o;
        o.x = packbf(fmaxf(o0, 0.f), fmaxf(o1, 0.f));
        o.y = packbf(fmaxf(o2, 0.f), fmaxf(o3, 0.f));
        H0[(size_t)n2 * 32 + g] = o;
    }
}

// ---------------- layer 1 aggregation (round-6 geometry, 4 nodes/block) ------
// Wave per node; lane h=lane&31 owns 4 channels; head = h>>3 (3-shfl reduce).
// Halves x 2 streams = 4 edges in flight. KV interleaved (256B K | 256B V).

__global__ __launch_bounds__(256) void agg1_kernel(
    const uint2* __restrict__ Q2, const unsigned short* __restrict__ KV,
    const float* __restrict__ We, const uint2* __restrict__ S2,
    uint2* __restrict__ Hout, const int* __restrict__ offsets,
    const int2* __restrict__ csr, int n_nodes) {
    int wid = threadIdx.x >> 6, lane = threadIdx.x & 63;
    int h = lane & 31, half = lane >> 5;
    int n = blockIdx.x * 4 + wid;
    if (n >= n_nodes) return;
    size_t rb = (size_t)n * 32;
    const float sc = RSC * LOG2E;
    uint2 qp = Q2[rb + h];
    float q0 = bflo(qp.x) * sc, q1 = bfhi(qp.x) * sc;
    float q2 = bflo(qp.y) * sc, q3 = bfhi(qp.y) * sc;
    float4 we4 = ((const float4*)We)[h];
    float qwe = fmaf(q3, we4.w, fmaf(q2, we4.z, fmaf(q1, we4.y, q0 * we4.x)));
    qwe += __shfl_xor(qwe, 1);
    qwe += __shfl_xor(qwe, 2);
    qwe += __shfl_xor(qwe, 4);
    int beg = __builtin_amdgcn_readfirstlane(offsets[n]);
    int end = __builtin_amdgcn_readfirstlane(offsets[n + 1]);
    float dA = 0.f, a0A = 0.f, a1A = 0.f, a2A = 0.f, a3A = 0.f, eA = 0.f;
    float dB = 0.f, a0B = 0.f, a1B = 0.f, a2B = 0.f, a3B = 0.f, eB = 0.f;
    int lane_b = h << 3;
    for (int j = beg + half; j < end; j += 4) {
        int jB = j + 2;
        bool vB = jB < end;
        int2 ceA = csr[j];
        int2 ceB = csr[vB ? jB : beg];
        float eaA = __int_as_float(ceA.y), eaB = __int_as_float(ceB.y);
        const char* kvA = (const char*)KV + (size_t)(unsigned)ceA.x + lane_b;
        const char* kvB = (const char*)KV + (size_t)(unsigned)ceB.x + lane_b;
        uint2 kA = *(const uint2*)kvA;
        uint2 vA2 = *(const uint2*)(kvA + 256);
        uint2 kB = *(const uint2*)kvB;
        uint2 vB2 = *(const uint2*)(kvB + 256);
        // stream A (j < end always)
        {
            float p = fmaf(q3, bfhi(kA.y), fmaf(q2, bflo(kA.y),
                      fmaf(q1, bfhi(kA.x), q0 * bflo(kA.x))));
            p += __shfl_xor(p, 1);
            p += __shfl_xor(p, 2);
            p += __shfl_xor(p, 4);
            float al = fminf(fmaf(eaA, qwe, p), 72.f);
            float w = EXP2F(al);
            dA += w;
            eA = fmaf(w, eaA, eA);
            a0A = fmaf(w, bflo(vA2.x), a0A);
            a1A = fmaf(w, bfhi(vA2.x), a1A);
            a2A = fmaf(w, bflo(vA2.y), a2A);
            a3A = fmaf(w, bfhi(vA2.y), a3A);
        }
        // stream B
        {
            float p = fmaf(q3, bfhi(kB.y), fmaf(q2, bflo(kB.y),
                      fmaf(q1, bfhi(kB.x), q0 * bflo(kB.x))));
            p += __shfl_xor(p, 1);
            p += __shfl_xor(p, 2);
            p += __shfl_xor(p, 4);
            float al = fmaf(eaB, qwe, p);
            al = vB ? al : -3.0e38f;
            float w = EXP2F(fminf(al, 72.f));
            dB += w;
            eB = fmaf(w, eaB, eB);
            a0B = fmaf(w, bflo(vB2.x), a0B);
            a1B = fmaf(w, bfhi(vB2.x), a1B);
            a2B = fmaf(w, bflo(vB2.y), a2B);
            a3B = fmaf(w, bfhi(vB2.y), a3B);
        }
    }
    float d = dA + dB, ea = eA + eB;
    float a0 = a0A + a0B, a1 = a1A + a1B, a2 = a2A + a2B, a3 = a3A + a3B;
    d += __shfl_xor(d, 32);
    ea += __shfl_xor(ea, 32);
    a0 += __shfl_xor(a0, 32);
    a1 += __shfl_xor(a1, 32);
    a2 += __shfl_xor(a2, 32);
    a3 += __shfl_xor(a3, 32);
    if (half == 0) {
        float inv = 1.f / (d + 1e-16f);
        uint2 sp = S2[rb + h];
        uint2 o;
        o.x = packbf(fmaxf(fmaf(fmaf(we4.x, ea, a0), inv, bflo(sp.x)), 0.f),
                     fmaxf(fmaf(fmaf(we4.y, ea, a1), inv, bfhi(sp.x)), 0.f));
        o.y = packbf(fmaxf(fmaf(fmaf(we4.z, ea, a2), inv, bflo(sp.y)), 0.f),
                     fmaxf(fmaf(fmaf(we4.w, ea, a3), inv, bfhi(sp.y)), 0.f));
        Hout[rb + h] = o;
    }
}

// ---------------- layer-1 projections: H0 @ {Wq1,Wk1,Wv1,Ws1} -------------

__global__ __launch_bounds__(256, 2) void gemm4_kernel(
    const unsigned short* __restrict__ Hb, int n_nodes,
    const unsigned short* __restrict__ wpk,
    const float* __restrict__ B0, unsigned short* __restrict__ O0, int ld0,
    const float* __restrict__ B1, unsigned short* __restrict__ O1, int ld1,
    const float* __restrict__ B2, unsigned short* __restrict__ O2, int ld2,
    const float* __restrict__ B3, unsigned short* __restrict__ O3, int ld3) {
    __shared__ __align__(16) unsigned short wbuf[16384];
    __shared__ __align__(16) char tbuf[128 * 272];
    int tid = threadIdx.x;
    int wid = tid >> 6, lane = tid & 63;
    int lr = lane & 15, lk = lane >> 4;
    int nblk = blockIdx.x * 128;

    s16x8 b[2][4];
#pragma unroll
    for (int nt = 0; nt < 2; ++nt) {
        int row = min(nblk + wid * 32 + nt * 16 + lr, n_nodes - 1);
        const s16x8* hp = (const s16x8*)(Hb + (size_t)row * 128);
#pragma unroll
        for (int kc = 0; kc < 4; ++kc) b[nt][kc] = hp[kc * 4 + lk];
    }
    const float* Bm[4] = {B0, B1, B2, B3};
    unsigned short* Om[4] = {O0, O1, O2, O3};
    int ldm[4] = {ld0, ld1, ld2, ld3};

#pragma unroll
    for (int i = 0; i < 8; ++i) {
        int c = i * 256 + tid;
        ((uint4*)wbuf)[c] = ((const uint4*)wpk)[c];
    }
#pragma unroll
    for (int mm = 0; mm < 4; ++mm) {
        __syncthreads();
        f32x4 acc[2][8];
#pragma unroll
        for (int nt = 0; nt < 2; ++nt)
#pragma unroll
            for (int ct = 0; ct < 8; ++ct) acc[nt][ct] = (f32x4){0.f, 0.f, 0.f, 0.f};
#pragma unroll
        for (int kc = 0; kc < 4; ++kc) {
#pragma unroll
            for (int ct = 0; ct < 8; ++ct) {
                s16x8 a = ((const s16x8*)wbuf)[(kc * 8 + ct) * 64 + lane];
                acc[0][ct] = __builtin_amdgcn_mfma_f32_16x16x32_bf16(a, b[0][kc], acc[0][ct], 0, 0, 0);
                acc[1][ct] = __builtin_amdgcn_mfma_f32_16x16x32_bf16(a, b[1][kc], acc[1][ct], 0, 0, 0);
            }
        }
        const float* Bp = Bm[mm];
#pragma unroll
        for (int ct = 0; ct < 8; ++ct) {
            float4 bb = *(const float4*)(Bp + ct * 16 + lk * 4);
#pragma unroll
            for (int nt = 0; nt < 2; ++nt) {
                int rnode = wid * 32 + nt * 16 + lr;
                uint2 o;
                o.x = packbf(acc[nt][ct][0] + bb.x, acc[nt][ct][1] + bb.y);
                o.y = packbf(acc[nt][ct][2] + bb.z, acc[nt][ct][3] + bb.w);
                *(uint2*)(tbuf + rnode * 272 + ct * 32 + lk * 8) = o;
            }
        }
        __syncthreads();
        unsigned short* Op = Om[mm];
        int ld = ldm[mm];
#pragma unroll
        for (int i = 0; i < 8; ++i) {
            int chunk = i * 256 + tid;
            int nd = chunk >> 4, c16 = chunk & 15;
            int ng = nblk + nd;
            uint4 v = *(const uint4*)(tbuf + nd * 272 + c16 * 16);
            if (ng < n_nodes) *(uint4*)(Op + (size_t)ng * ld + c16 * 8) = v;
        }
        if (mm < 3) {
            const uint4* ws = (const uint4*)(wpk + (mm + 1) * 16384);
#pragma unroll
            for (int i = 0; i < 8; ++i) {
                int c = i * 256 + tid;
                ((uint4*)wbuf)[c] = ws[c];
            }
        }
    }
}

// ---------------- fused classifier (weights LDS-staged) ----------------

__global__ __launch_bounds__(256, 2) void classifier_kernel(
    const unsigned short* __restrict__ H1b, int n_nodes,
    const unsigned short* __restrict__ wc1p, const float* __restrict__ bc1,
    const unsigned short* __restrict__ wc2p, const float* __restrict__ bc2,
    const float* __restrict__ Wc3, const float* __restrict__ bc3,
    float* __restrict__ out) {
    __shared__ __align__(16) unsigned short w1s[16384];  // 32 KB
    __shared__ __align__(16) unsigned short w2s[8192];   // 16 KB
    __shared__ __align__(16) char lds_raw[4 * 16 * 272]; // 17 KB
    int tid = threadIdx.x;
    int wid = tid >> 6, lane = tid & 63;
    int lr = lane & 15, lk = lane >> 4;
    int nb = blockIdx.x * 64 + wid * 16;
    char* tile = lds_raw + wid * 16 * 272;

#pragma unroll
    for (int i = 0; i < 8; ++i)
        ((uint4*)w1s)[i * 256 + tid] = ((const uint4*)wc1p)[i * 256 + tid];
#pragma unroll
    for (int i = 0; i < 4; ++i)
        ((uint4*)w2s)[i * 256 + tid] = ((const uint4*)wc2p)[i * 256 + tid];

    s16x8 b[4];
    {
        int row = min(nb + lr, n_nodes - 1);
        const s16x8* hp = (const s16x8*)(H1b + (size_t)row * 128);
#pragma unroll
        for (int kc = 0; kc < 4; ++kc) b[kc] = hp[kc * 4 + lk];
    }
    __syncthreads();
    f32x4 acc[8];
#pragma unroll
    for (int ct = 0; ct < 8; ++ct) acc[ct] = (f32x4){0.f, 0.f, 0.f, 0.f};
#pragma unroll
    for (int kc = 0; kc < 4; ++kc)
#pragma unroll
        for (int ct = 0; ct < 8; ++ct) {
            s16x8 a = ((const s16x8*)w1s)[(kc * 8 + ct) * 64 + lane];
            acc[ct] = __builtin_amdgcn_mfma_f32_16x16x32_bf16(a, b[kc], acc[ct], 0, 0, 0);
        }
#pragma unroll
    for (int ct = 0; ct < 8; ++ct) {
        float4 bb = *(const float4*)(bc1 + ct * 16 + lk * 4);
        uint2 o;
        o.x = packbf(fmaxf(acc[ct][0] + bb.x, 0.f), fmaxf(acc[ct][1] + bb.y, 0.f));
        o.y = packbf(fmaxf(acc[ct][2] + bb.z, 0.f), fmaxf(acc[ct][3] + bb.w, 0.f));
        *(uint2*)(tile + lr * 272 + ct * 32 + lk * 8) = o;
    }
    __syncthreads();
    s16x8 b2[4];
#pragma unroll
    for (int kc = 0; kc < 4; ++kc)
        b2[kc] = *(const s16x8*)(tile + lr * 272 + kc * 64 + lk * 16);
    f32x4 acc2[4];
#pragma unroll
    for (int ct = 0; ct < 4; ++ct) acc2[ct] = (f32x4){0.f, 0.f, 0.f, 0.f};
#pragma unroll
    for (int kc = 0; kc < 4; ++kc)
#pragma unroll
        for (int ct = 0; ct < 4; ++ct) {
            s16x8 a = ((const s16x8*)w2s)[(kc * 4 + ct) * 64 + lane];
            acc2[ct] = __builtin_amdgcn_mfma_f32_16x16x32_bf16(a, b2[kc], acc2[ct], 0, 0, 0);
        }
    float part = 0.f;
#pragma unroll
    for (int ct = 0; ct < 4; ++ct) {
        int ch0 = ct * 16 + lk * 4;
        float4 bb = *(const float4*)(bc2 + ch0);
        float4 w3 = *(const float4*)(Wc3 + ch0);
        part += fmaxf(acc2[ct][0] + bb.x, 0.f) * w3.x;
        part += fmaxf(acc2[ct][1] + bb.y, 0.f) * w3.y;
        part += fmaxf(acc2[ct][2] + bb.z, 0.f) * w3.z;
        part += fmaxf(acc2[ct][3] + bb.w, 0.f) * w3.w;
    }
    part += __shfl_xor(part, 16);
    part += __shfl_xor(part, 32);
    if (lk == 0) {
        int node = nb + lr;
        if (node < n_nodes) out[node] = part + bc3[0];
    }
}

// ---------------- launch ----------------

extern "C" void kernel_launch(void* const* d_in, const int* in_sizes, int n_in,
                              void* d_out, int out_size, void* d_ws, size_t ws_size,
                              hipStream_t stream) {
    const float* x = (const float*)d_in[0];
    const int* ei = (const int*)d_in[1];
    const float* ea = (const float*)d_in[2];
    const float *Wq0 = (const float*)d_in[3], *bq0 = (const float*)d_in[4];
    const float *Wk0 = (const float*)d_in[5], *bk0 = (const float*)d_in[6];
    const float *Wv0 = (const float*)d_in[7], *bv0 = (const float*)d_in[8];
    const float* We0 = (const float*)d_in[9];
    const float *Ws0 = (const float*)d_in[10], *bs0 = (const float*)d_in[11];
    const float *Wq1 = (const float*)d_in[12], *bq1 = (const float*)d_in[13];
    const float *Wk1 = (const float*)d_in[14], *bk1 = (const float*)d_in[15];
    const float *Wv1 = (const float*)d_in[16], *bv1 = (const float*)d_in[17];
    const float* We1 = (const float*)d_in[18];
    const float *Ws1 = (const float*)d_in[19], *bs1 = (const float*)d_in[20];
    const float *Wc1 = (const float*)d_in[21], *bc1 = (const float*)d_in[22];
    const float *Wc2 = (const float*)d_in[23], *bc2 = (const float*)d_in[24];
    const float *Wc3 = (const float*)d_in[25], *bc3 = (const float*)d_in[26];

    const int N = in_sizes[0] / 2;  // 100000
    const int E = in_sizes[2];      // 800000
    const int* src = ei;
    const int* dst = ei + E;

    // workspace layout
    size_t NM = (size_t)N * 128;
    float* gcoef = (float*)d_ws;                      // 64 floats
    unsigned short* H0b = (unsigned short*)(gcoef + 64);
    unsigned short* Qb = H0b + NM;
    unsigned short* KV = Qb + NM;    // [N][256] ushort: K row | V row
    unsigned short* S1b = KV + 2 * NM;
    unsigned short* wpk = S1b + NM;  // 90112 bf16 packed weights
    int* counts = (int*)(wpk + 90112);
    int* offsets = counts + N;       // N+1
    int2* csr = (int2*)(offsets + N + 2);
    size_t need = (size_t)((char*)(csr + E) - (char*)d_ws);
    if (need > ws_size) {
        fprintf(stderr, "kernel_launch: ws too small (need %zu, have %zu)\n", need, ws_size);
        return;
    }

    const int NB_HIST = cdiv(E, 256);  // 3125

    // ---- CSR build + weight prep (4 dispatches) ----
    hipMemsetAsync(counts, 0, (size_t)N * 4, stream);
    histpack_kernel<<<NB_HIST + 353, 256, 0, stream>>>(
        dst, E, counts, NB_HIST, Wq1, Wk1, Wv1, Ws1, Wc1, Wc2, wpk,
        Wq0, bq0, Wk0, bk0, We0, gcoef);
    scan1_kernel<<<1, 1024, 0, stream>>>(counts, N, offsets);
    scatter_kernel<<<NB_HIST, 256, 0, stream>>>(src, dst, ea, E, offsets, counts, csr);

    // ---- layer 0 (rank-collapsed, fused agg+expand) ----
    agg0x_kernel<<<cdiv(N, 64), 256, 0, stream>>>(
        x, gcoef, Wv0, bv0, We0, Ws0, bs0, (uint2*)H0b, offsets, csr, N);

    // ---- layer 1 ----
    gemm4_kernel<<<cdiv(N, 128), 256, 0, stream>>>(
        H0b, N, wpk,
        bq1, Qb, 128,
        bk1, KV, 256,        // K half of KV row
        bv1, KV + 128, 256,  // V half of KV row
        bs1, S1b, 128);
    agg1_kernel<<<cdiv(N, 4), 256, 0, stream>>>(
        (const uint2*)Qb, KV, We1, (const uint2*)S1b, (uint2*)S1b,
        offsets, csr, N);

    // ---- classifier (fused) ----
    classifier_kernel<<<cdiv(N, 64), 256, 0, stream>>>(
        S1b, N, wpk + 65536, bc1, wpk + 81920, bc2, Wc3, bc3, (float*)d_out);
}

// Round 10
// 336.702 us; speedup vs baseline: 1.3749x; 1.3749x over previous
//
#include <hip/hip_runtime.h>
#include <hip/hip_bf16.h>
#include <cstdio>
#include <cstdint>

// GAT_37580963840365: 2-layer TransformerConv (H=4, C=32, HC=128) + MLP head.
// Softmax WITHOUT max-subtraction (shift-invariant, exp2-domain, clamp 2^72)
// -> all edge weights independent. Layer 0 collapsed to bilinear form
// (G = 3x4/head) with fused scalar-agg + expand (LDS handoff). Layer 1:
// LDS-staged MFMA GEMM -> KV interleaved rows; agg1 = round-6 geometry
// (32 lanes/edge, 4 edges in flight) in 256-thr blocks. Classifier fused with
// LDS-staged weights. Multi-block 3-kernel scan (r8's 1-block scan was 137us).

typedef short s16x8 __attribute__((ext_vector_type(8)));
typedef float f32x4 __attribute__((ext_vector_type(4)));

static inline int cdiv(int a, int b) { return (a + b - 1) / b; }

#define EXP2F(x) __builtin_amdgcn_exp2f(x)
#define LOG2E 1.4426950408889634f
#define RSC 0.17677669529663687f  // 1/sqrt(32)

__device__ __forceinline__ float bflo(unsigned u) {
    union { unsigned i; float f; } x; x.i = u << 16; return x.f;
}
__device__ __forceinline__ float bfhi(unsigned u) {
    union { unsigned i; float f; } x; x.i = u & 0xffff0000u; return x.f;
}
__device__ __forceinline__ unsigned short f2b(float f) {
    __hip_bfloat16 h = __float2bfloat16(f);
    return *reinterpret_cast<unsigned short*>(&h);
}
__device__ __forceinline__ unsigned packbf(float lo, float hi) {
    return (unsigned)f2b(lo) | ((unsigned)f2b(hi) << 16);
}

// ---------------- hist + weight pack + layer-0 bilinear coefs (one dispatch) --

__global__ __launch_bounds__(256) void histpack_kernel(
    const int* __restrict__ dst, int E, int* __restrict__ counts, int nb_hist,
    const float* __restrict__ Wq1, const float* __restrict__ Wk1,
    const float* __restrict__ Wv1, const float* __restrict__ Ws1,
    const float* __restrict__ Wc1, const float* __restrict__ Wc2,
    unsigned short* __restrict__ wpk,
    const float* __restrict__ Wq0, const float* __restrict__ bq0,
    const float* __restrict__ Wk0, const float* __restrict__ bk0,
    const float* __restrict__ We0, float* __restrict__ gcoef) {
    int bid = blockIdx.x;
    if (bid < nb_hist) {  // histogram part
        int e = bid * 256 + threadIdx.x;
        if (e < E) atomicAdd(&counts[dst[e]], 1);
        return;
    }
    int pb = bid - nb_hist;
    if (pb == 352) {  // gcoef: G[h][i][j] = rsc*log2e * dot32(A_i, B_j)
        int t = threadIdx.x;
        if (t < 48) {
            int h = t / 12, r = t % 12, i = r >> 2, j = r & 3;
            const float* A = (i == 0) ? Wq0 : (i == 1) ? (Wq0 + 128) : bq0;
            const float* B = (j == 0) ? Wk0 : (j == 1) ? (Wk0 + 128) : (j == 2) ? We0 : bk0;
            float s = 0.f;
            for (int c = 0; c < 32; ++c) s += A[h * 32 + c] * B[h * 32 + c];
            gcoef[h * 12 + i * 4 + j] = s * (RSC * LOG2E);
        }
        return;
    }
    // pack: wpk[((kc*CT+ct)*64+lane)*8+j] = bf16(W[kc*32+(lane>>4)*8+j][ct*16+(lane&15)])
    int idx = pb * 256 + threadIdx.x;
    int local, COLS;
    const float* W;
    if (idx < 81920) {
        int m = idx >> 14;
        local = idx & 16383;
        COLS = 128;
        W = (m == 0) ? Wq1 : (m == 1) ? Wk1 : (m == 2) ? Wv1 : (m == 3) ? Ws1 : Wc1;
    } else {
        local = idx - 81920;
        COLS = 64;
        W = Wc2;
    }
    int CT = COLS >> 4;
    int j = local & 7, lane = (local >> 3) & 63, t = local >> 9;
    int ct = t % CT, kc = t / CT;
    int k = kc * 32 + ((lane >> 4) << 3) + j;
    int nn = (ct << 4) + (lane & 15);
    wpk[idx] = f2b(W[k * COLS + nn]);
}

// ---------------- multi-block scan (3 kernels, proven ~10us) ----------------

__global__ __launch_bounds__(256) void scan_sums(const int* __restrict__ counts, int n,
                                                 int* __restrict__ bsums) {
    __shared__ int red[256];
    int base = blockIdx.x * 2048 + threadIdx.x * 8;
    int s = 0;
#pragma unroll
    for (int j = 0; j < 8; ++j) {
        int i = base + j;
        if (i < n) s += counts[i];
    }
    red[threadIdx.x] = s;
    __syncthreads();
    for (int off = 128; off > 0; off >>= 1) {
        if (threadIdx.x < off) red[threadIdx.x] += red[threadIdx.x + off];
        __syncthreads();
    }
    if (threadIdx.x == 0) bsums[blockIdx.x] = red[0];
}

__global__ void scan_mid(int* bsums, int nb, int* offsets, int n) {
    if (blockIdx.x == 0 && threadIdx.x == 0) {
        int run = 0;
        for (int i = 0; i < nb; ++i) { int t = bsums[i]; bsums[i] = run; run += t; }
        offsets[n] = run;
    }
}

__global__ __launch_bounds__(256) void scan_out(const int* __restrict__ counts, int n,
                                                const int* __restrict__ bsums,
                                                int* __restrict__ offsets) {
    __shared__ int tsum[256];
    int base = blockIdx.x * 2048 + threadIdx.x * 8;
    int v[8];
    int s = 0;
#pragma unroll
    for (int j = 0; j < 8; ++j) {
        int i = base + j;
        v[j] = (i < n) ? counts[i] : 0;
        s += v[j];
    }
    tsum[threadIdx.x] = s;
    __syncthreads();
    for (int off = 1; off < 256; off <<= 1) {
        int x = (threadIdx.x >= (unsigned)off) ? tsum[threadIdx.x - off] : 0;
        __syncthreads();
        tsum[threadIdx.x] += x;
        __syncthreads();
    }
    int excl = tsum[threadIdx.x] - s + bsums[blockIdx.x];
#pragma unroll
    for (int j = 0; j < 8; ++j) {
        int i = base + j;
        if (i < n) { offsets[i] = excl; excl += v[j]; }
    }
}

// scatter: consumes counts via atomicSub; packs {src*512, ea_bits} into int2.
__global__ __launch_bounds__(256) void scatter_kernel(const int* __restrict__ src,
                                                      const int* __restrict__ dst,
                                                      const float* __restrict__ ea, int E,
                                                      const int* __restrict__ offsets,
                                                      int* __restrict__ counts,
                                                      int2* __restrict__ csr) {
    int e = blockIdx.x * 256 + threadIdx.x;
    if (e >= E) return;
    int d = dst[e];
    int r = atomicSub(&counts[d], 1);
    int p = offsets[d] + r - 1;
    csr[p] = make_int2(src[e] << 9, __float_as_int(ea[e]));
}

// ---------------- layer 0: fused scalar-agg + expand ----------------

__global__ __launch_bounds__(256) void agg0x_kernel(
    const float* __restrict__ x, const float* __restrict__ gcoef,
    const float* __restrict__ Wv, const float* __restrict__ bv,
    const float* __restrict__ We, const float* __restrict__ Ws,
    const float* __restrict__ bs, uint2* __restrict__ H0,
    const int* __restrict__ offsets, const int2* __restrict__ csr, int n_nodes) {
    __shared__ float4 sm[256];  // [64 nodes][4 heads]
    int t = threadIdx.x;
    int nb = blockIdx.x * 64;
    {
        int n = nb + (t >> 2), h = t & 3;
        if (n < n_nodes) {
            float2 xn = ((const float2*)x)[n];
            const float4* G4 = (const float4*)gcoef;
            float4 g0 = G4[h * 3 + 0], g1 = G4[h * 3 + 1], g2 = G4[h * 3 + 2];
            float c0 = fmaf(xn.y, g1.x, fmaf(xn.x, g0.x, g2.x));
            float c1 = fmaf(xn.y, g1.y, fmaf(xn.x, g0.y, g2.y));
            float c2 = fmaf(xn.y, g1.z, fmaf(xn.x, g0.z, g2.z));
            float c3 = fmaf(xn.y, g1.w, fmaf(xn.x, g0.w, g2.w));
            int beg = offsets[n], end = offsets[n + 1];
            float d = 0.f, X0 = 0.f, X1 = 0.f, EA = 0.f;
            for (int j = beg; j < end; ++j) {
                int2 ce = csr[j];
                float e = __int_as_float(ce.y);
                float2 xs = *(const float2*)((const char*)x + (((unsigned)ce.x) >> 6));
                float al = fmaf(c0, xs.x, fmaf(c1, xs.y, fmaf(c2, e, c3)));
                float w = EXP2F(fminf(al, 72.f));
                d += w;
                X0 = fmaf(w, xs.x, X0);
                X1 = fmaf(w, xs.y, X1);
                EA = fmaf(w, e, EA);
            }
            sm[t] = make_float4(X0, X1, EA, d);
        }
    }
    __syncthreads();
    int g = t & 31;
    float4 wv0 = ((const float4*)Wv)[g], wv1 = ((const float4*)(Wv + 128))[g];
    float4 we = ((const float4*)We)[g], bv4 = ((const float4*)bv)[g];
    float4 ws0 = ((const float4*)Ws)[g], ws1 = ((const float4*)(Ws + 128))[g];
    float4 bs4 = ((const float4*)bs)[g];
    int h = g >> 3;
#pragma unroll
    for (int it = 0; it < 8; ++it) {
        int ln = it * 8 + (t >> 5);
        int n2 = nb + ln;
        if (n2 >= n_nodes) break;
        float4 ag = sm[ln * 4 + h];
        float inv = 1.f / (ag.w + 1e-16f);
        float2 xn = ((const float2*)x)[n2];
        float o0 = fmaf(wv0.x, ag.x, fmaf(wv1.x, ag.y, fmaf(we.x, ag.z, bv4.x * ag.w))) * inv
                 + fmaf(xn.x, ws0.x, fmaf(xn.y, ws1.x, bs4.x));
        float o1 = fmaf(wv0.y, ag.x, fmaf(wv1.y, ag.y, fmaf(we.y, ag.z, bv4.y * ag.w))) * inv
                 + fmaf(xn.x, ws0.y, fmaf(xn.y, ws1.y, bs4.y));
        float o2 = fmaf(wv0.z, ag.x, fmaf(wv1.z, ag.y, fmaf(we.z, ag.z, bv4.z * ag.w))) * inv
                 + fmaf(xn.x, ws0.z, fmaf(xn.y, ws1.z, bs4.z));
        float o3 = fmaf(wv0.w, ag.x, fmaf(wv1.w, ag.y, fmaf(we.w, ag.z, bv4.w * ag.w))) * inv
                 + fmaf(xn.x, ws0.w, fmaf(xn.y, ws1.w, bs4.w));
        uint2 o;
        o.x = packbf(fmaxf(o0, 0.f), fmaxf(o1, 0.f));
        o.y = packbf(fmaxf(o2, 0.f), fmaxf(o3, 0.f));
        H0[(size_t)n2 * 32 + g] = o;
    }
}

// ---------------- layer 1 aggregation (round-6 geometry, 4 nodes/block) ------

__global__ __launch_bounds__(256) void agg1_kernel(
    const uint2* __restrict__ Q2, const unsigned short* __restrict__ KV,
    const float* __restrict__ We, const uint2* __restrict__ S2,
    uint2* __restrict__ Hout, const int* __restrict__ offsets,
    const int2* __restrict__ csr, int n_nodes) {
    int wid = threadIdx.x >> 6, lane = threadIdx.x & 63;
    int h = lane & 31, half = lane >> 5;
    int n = blockIdx.x * 4 + wid;
    if (n >= n_nodes) return;
    size_t rb = (size_t)n * 32;
    const float sc = RSC * LOG2E;
    uint2 qp = Q2[rb + h];
    float q0 = bflo(qp.x) * sc, q1 = bfhi(qp.x) * sc;
    float q2 = bflo(qp.y) * sc, q3 = bfhi(qp.y) * sc;
    float4 we4 = ((const float4*)We)[h];
    float qwe = fmaf(q3, we4.w, fmaf(q2, we4.z, fmaf(q1, we4.y, q0 * we4.x)));
    qwe += __shfl_xor(qwe, 1);
    qwe += __shfl_xor(qwe, 2);
    qwe += __shfl_xor(qwe, 4);
    int beg = __builtin_amdgcn_readfirstlane(offsets[n]);
    int end = __builtin_amdgcn_readfirstlane(offsets[n + 1]);
    float dA = 0.f, a0A = 0.f, a1A = 0.f, a2A = 0.f, a3A = 0.f, eA = 0.f;
    float dB = 0.f, a0B = 0.f, a1B = 0.f, a2B = 0.f, a3B = 0.f, eB = 0.f;
    int lane_b = h << 3;
    for (int j = beg + half; j < end; j += 4) {
        int jB = j + 2;
        bool vB = jB < end;
        int2 ceA = csr[j];
        int2 ceB = csr[vB ? jB : beg];
        float eaA = __int_as_float(ceA.y), eaB = __int_as_float(ceB.y);
        const char* kvA = (const char*)KV + (size_t)(unsigned)ceA.x + lane_b;
        const char* kvB = (const char*)KV + (size_t)(unsigned)ceB.x + lane_b;
        uint2 kA = *(const uint2*)kvA;
        uint2 vA2 = *(const uint2*)(kvA + 256);
        uint2 kB = *(const uint2*)kvB;
        uint2 vB2 = *(const uint2*)(kvB + 256);
        {
            float p = fmaf(q3, bfhi(kA.y), fmaf(q2, bflo(kA.y),
                      fmaf(q1, bfhi(kA.x), q0 * bflo(kA.x))));
            p += __shfl_xor(p, 1);
            p += __shfl_xor(p, 2);
            p += __shfl_xor(p, 4);
            float al = fminf(fmaf(eaA, qwe, p), 72.f);
            float w = EXP2F(al);
            dA += w;
            eA = fmaf(w, eaA, eA);
            a0A = fmaf(w, bflo(vA2.x), a0A);
            a1A = fmaf(w, bfhi(vA2.x), a1A);
            a2A = fmaf(w, bflo(vA2.y), a2A);
            a3A = fmaf(w, bfhi(vA2.y), a3A);
        }
        {
            float p = fmaf(q3, bfhi(kB.y), fmaf(q2, bflo(kB.y),
                      fmaf(q1, bfhi(kB.x), q0 * bflo(kB.x))));
            p += __shfl_xor(p, 1);
            p += __shfl_xor(p, 2);
            p += __shfl_xor(p, 4);
            float al = fmaf(eaB, qwe, p);
            al = vB ? al : -3.0e38f;
            float w = EXP2F(fminf(al, 72.f));
            dB += w;
            eB = fmaf(w, eaB, eB);
            a0B = fmaf(w, bflo(vB2.x), a0B);
            a1B = fmaf(w, bfhi(vB2.x), a1B);
            a2B = fmaf(w, bflo(vB2.y), a2B);
            a3B = fmaf(w, bfhi(vB2.y), a3B);
        }
    }
    float d = dA + dB, ea = eA + eB;
    float a0 = a0A + a0B, a1 = a1A + a1B, a2 = a2A + a2B, a3 = a3A + a3B;
    d += __shfl_xor(d, 32);
    ea += __shfl_xor(ea, 32);
    a0 += __shfl_xor(a0, 32);
    a1 += __shfl_xor(a1, 32);
    a2 += __shfl_xor(a2, 32);
    a3 += __shfl_xor(a3, 32);
    if (half == 0) {
        float inv = 1.f / (d + 1e-16f);
        uint2 sp = S2[rb + h];
        uint2 o;
        o.x = packbf(fmaxf(fmaf(fmaf(we4.x, ea, a0), inv, bflo(sp.x)), 0.f),
                     fmaxf(fmaf(fmaf(we4.y, ea, a1), inv, bfhi(sp.x)), 0.f));
        o.y = packbf(fmaxf(fmaf(fmaf(we4.z, ea, a2), inv, bflo(sp.y)), 0.f),
                     fmaxf(fmaf(fmaf(we4.w, ea, a3), inv, bfhi(sp.y)), 0.f));
        Hout[rb + h] = o;
    }
}

// ---------------- layer-1 projections: H0 @ {Wq1,Wk1,Wv1,Ws1} -------------

__global__ __launch_bounds__(256, 2) void gemm4_kernel(
    const unsigned short* __restrict__ Hb, int n_nodes,
    const unsigned short* __restrict__ wpk,
    const float* __restrict__ B0, unsigned short* __restrict__ O0, int ld0,
    const float* __restrict__ B1, unsigned short* __restrict__ O1, int ld1,
    const float* __restrict__ B2, unsigned short* __restrict__ O2, int ld2,
    const float* __restrict__ B3, unsigned short* __restrict__ O3, int ld3) {
    __shared__ __align__(16) unsigned short wbuf[16384];
    __shared__ __align__(16) char tbuf[128 * 272];
    int tid = threadIdx.x;
    int wid = tid >> 6, lane = tid & 63;
    int lr = lane & 15, lk = lane >> 4;
    int nblk = blockIdx.x * 128;

    s16x8 b[2][4];
#pragma unroll
    for (int nt = 0; nt < 2; ++nt) {
        int row = min(nblk + wid * 32 + nt * 16 + lr, n_nodes - 1);
        const s16x8* hp = (const s16x8*)(Hb + (size_t)row * 128);
#pragma unroll
        for (int kc = 0; kc < 4; ++kc) b[nt][kc] = hp[kc * 4 + lk];
    }
    const float* Bm[4] = {B0, B1, B2, B3};
    unsigned short* Om[4] = {O0, O1, O2, O3};
    int ldm[4] = {ld0, ld1, ld2, ld3};

#pragma unroll
    for (int i = 0; i < 8; ++i) {
        int c = i * 256 + tid;
        ((uint4*)wbuf)[c] = ((const uint4*)wpk)[c];
    }
#pragma unroll
    for (int mm = 0; mm < 4; ++mm) {
        __syncthreads();
        f32x4 acc[2][8];
#pragma unroll
        for (int nt = 0; nt < 2; ++nt)
#pragma unroll
            for (int ct = 0; ct < 8; ++ct) acc[nt][ct] = (f32x4){0.f, 0.f, 0.f, 0.f};
#pragma unroll
        for (int kc = 0; kc < 4; ++kc) {
#pragma unroll
            for (int ct = 0; ct < 8; ++ct) {
                s16x8 a = ((const s16x8*)wbuf)[(kc * 8 + ct) * 64 + lane];
                acc[0][ct] = __builtin_amdgcn_mfma_f32_16x16x32_bf16(a, b[0][kc], acc[0][ct], 0, 0, 0);
                acc[1][ct] = __builtin_amdgcn_mfma_f32_16x16x32_bf16(a, b[1][kc], acc[1][ct], 0, 0, 0);
            }
        }
        const float* Bp = Bm[mm];
#pragma unroll
        for (int ct = 0; ct < 8; ++ct) {
            float4 bb = *(const float4*)(Bp + ct * 16 + lk * 4);
#pragma unroll
            for (int nt = 0; nt < 2; ++nt) {
                int rnode = wid * 32 + nt * 16 + lr;
                uint2 o;
                o.x = packbf(acc[nt][ct][0] + bb.x, acc[nt][ct][1] + bb.y);
                o.y = packbf(acc[nt][ct][2] + bb.z, acc[nt][ct][3] + bb.w);
                *(uint2*)(tbuf + rnode * 272 + ct * 32 + lk * 8) = o;
            }
        }
        __syncthreads();
        unsigned short* Op = Om[mm];
        int ld = ldm[mm];
#pragma unroll
        for (int i = 0; i < 8; ++i) {
            int chunk = i * 256 + tid;
            int nd = chunk >> 4, c16 = chunk & 15;
            int ng = nblk + nd;
            uint4 v = *(const uint4*)(tbuf + nd * 272 + c16 * 16);
            if (ng < n_nodes) *(uint4*)(Op + (size_t)ng * ld + c16 * 8) = v;
        }
        if (mm < 3) {
            const uint4* ws = (const uint4*)(wpk + (mm + 1) * 16384);
#pragma unroll
            for (int i = 0; i < 8; ++i) {
                int c = i * 256 + tid;
                ((uint4*)wbuf)[c] = ws[c];
            }
        }
    }
}

// ---------------- fused classifier (weights LDS-staged) ----------------

__global__ __launch_bounds__(256, 2) void classifier_kernel(
    const unsigned short* __restrict__ H1b, int n_nodes,
    const unsigned short* __restrict__ wc1p, const float* __restrict__ bc1,
    const unsigned short* __restrict__ wc2p, const float* __restrict__ bc2,
    const float* __restrict__ Wc3, const float* __restrict__ bc3,
    float* __restrict__ out) {
    __shared__ __align__(16) unsigned short w1s[16384];  // 32 KB
    __shared__ __align__(16) unsigned short w2s[8192];   // 16 KB
    __shared__ __align__(16) char lds_raw[4 * 16 * 272]; // 17 KB
    int tid = threadIdx.x;
    int wid = tid >> 6, lane = tid & 63;
    int lr = lane & 15, lk = lane >> 4;
    int nb = blockIdx.x * 64 + wid * 16;
    char* tile = lds_raw + wid * 16 * 272;

#pragma unroll
    for (int i = 0; i < 8; ++i)
        ((uint4*)w1s)[i * 256 + tid] = ((const uint4*)wc1p)[i * 256 + tid];
#pragma unroll
    for (int i = 0; i < 4; ++i)
        ((uint4*)w2s)[i * 256 + tid] = ((const uint4*)wc2p)[i * 256 + tid];

    s16x8 b[4];
    {
        int row = min(nb + lr, n_nodes - 1);
        const s16x8* hp = (const s16x8*)(H1b + (size_t)row * 128);
#pragma unroll
        for (int kc = 0; kc < 4; ++kc) b[kc] = hp[kc * 4 + lk];
    }
    __syncthreads();
    f32x4 acc[8];
#pragma unroll
    for (int ct = 0; ct < 8; ++ct) acc[ct] = (f32x4){0.f, 0.f, 0.f, 0.f};
#pragma unroll
    for (int kc = 0; kc < 4; ++kc)
#pragma unroll
        for (int ct = 0; ct < 8; ++ct) {
            s16x8 a = ((const s16x8*)w1s)[(kc * 8 + ct) * 64 + lane];
            acc[ct] = __builtin_amdgcn_mfma_f32_16x16x32_bf16(a, b[kc], acc[ct], 0, 0, 0);
        }
#pragma unroll
    for (int ct = 0; ct < 8; ++ct) {
        float4 bb = *(const float4*)(bc1 + ct * 16 + lk * 4);
        uint2 o;
        o.x = packbf(fmaxf(acc[ct][0] + bb.x, 0.f), fmaxf(acc[ct][1] + bb.y, 0.f));
        o.y = packbf(fmaxf(acc[ct][2] + bb.z, 0.f), fmaxf(acc[ct][3] + bb.w, 0.f));
        *(uint2*)(tile + lr * 272 + ct * 32 + lk * 8) = o;
    }
    __syncthreads();
    s16x8 b2[4];
#pragma unroll
    for (int kc = 0; kc < 4; ++kc)
        b2[kc] = *(const s16x8*)(tile + lr * 272 + kc * 64 + lk * 16);
    f32x4 acc2[4];
#pragma unroll
    for (int ct = 0; ct < 4; ++ct) acc2[ct] = (f32x4){0.f, 0.f, 0.f, 0.f};
#pragma unroll
    for (int kc = 0; kc < 4; ++kc)
#pragma unroll
        for (int ct = 0; ct < 4; ++ct) {
            s16x8 a = ((const s16x8*)w2s)[(kc * 4 + ct) * 64 + lane];
            acc2[ct] = __builtin_amdgcn_mfma_f32_16x16x32_bf16(a, b2[kc], acc2[ct], 0, 0, 0);
        }
    float part = 0.f;
#pragma unroll
    for (int ct = 0; ct < 4; ++ct) {
        int ch0 = ct * 16 + lk * 4;
        float4 bb = *(const float4*)(bc2 + ch0);
        float4 w3 = *(const float4*)(Wc3 + ch0);
        part += fmaxf(acc2[ct][0] + bb.x, 0.f) * w3.x;
        part += fmaxf(acc2[ct][1] + bb.y, 0.f) * w3.y;
        part += fmaxf(acc2[ct][2] + bb.z, 0.f) * w3.z;
        part += fmaxf(acc2[ct][3] + bb.w, 0.f) * w3.w;
    }
    part += __shfl_xor(part, 16);
    part += __shfl_xor(part, 32);
    if (lk == 0) {
        int node = nb + lr;
        if (node < n_nodes) out[node] = part + bc3[0];
    }
}

// ---------------- launch ----------------

extern "C" void kernel_launch(void* const* d_in, const int* in_sizes, int n_in,
                              void* d_out, int out_size, void* d_ws, size_t ws_size,
                              hipStream_t stream) {
    const float* x = (const float*)d_in[0];
    const int* ei = (const int*)d_in[1];
    const float* ea = (const float*)d_in[2];
    const float *Wq0 = (const float*)d_in[3], *bq0 = (const float*)d_in[4];
    const float *Wk0 = (const float*)d_in[5], *bk0 = (const float*)d_in[6];
    const float *Wv0 = (const float*)d_in[7], *bv0 = (const float*)d_in[8];
    const float* We0 = (const float*)d_in[9];
    const float *Ws0 = (const float*)d_in[10], *bs0 = (const float*)d_in[11];
    const float *Wq1 = (const float*)d_in[12], *bq1 = (const float*)d_in[13];
    const float *Wk1 = (const float*)d_in[14], *bk1 = (const float*)d_in[15];
    const float *Wv1 = (const float*)d_in[16], *bv1 = (const float*)d_in[17];
    const float* We1 = (const float*)d_in[18];
    const float *Ws1 = (const float*)d_in[19], *bs1 = (const float*)d_in[20];
    const float *Wc1 = (const float*)d_in[21], *bc1 = (const float*)d_in[22];
    const float *Wc2 = (const float*)d_in[23], *bc2 = (const float*)d_in[24];
    const float *Wc3 = (const float*)d_in[25], *bc3 = (const float*)d_in[26];

    const int N = in_sizes[0] / 2;  // 100000
    const int E = in_sizes[2];      // 800000
    const int* src = ei;
    const int* dst = ei + E;

    // workspace layout
    size_t NM = (size_t)N * 128;
    float* gcoef = (float*)d_ws;                      // 64 floats
    unsigned short* H0b = (unsigned short*)(gcoef + 64);
    unsigned short* Qb = H0b + NM;
    unsigned short* KV = Qb + NM;    // [N][256] ushort: K row | V row
    unsigned short* S1b = KV + 2 * NM;
    unsigned short* wpk = S1b + NM;  // 90112 bf16 packed weights
    int* counts = (int*)(wpk + 90112);
    int* offsets = counts + N;       // N+1
    int* bsums = offsets + N + 2;    // up to 64
    int2* csr = (int2*)(bsums + 64);
    size_t need = (size_t)((char*)(csr + E) - (char*)d_ws);
    if (need > ws_size) {
        fprintf(stderr, "kernel_launch: ws too small (need %zu, have %zu)\n", need, ws_size);
        return;
    }

    const int NB_HIST = cdiv(E, 256);  // 3125
    const int NB_SCAN = cdiv(N, 2048); // 49

    // ---- CSR build + weight prep ----
    hipMemsetAsync(counts, 0, (size_t)N * 4, stream);
    histpack_kernel<<<NB_HIST + 353, 256, 0, stream>>>(
        dst, E, counts, NB_HIST, Wq1, Wk1, Wv1, Ws1, Wc1, Wc2, wpk,
        Wq0, bq0, Wk0, bk0, We0, gcoef);
    scan_sums<<<NB_SCAN, 256, 0, stream>>>(counts, N, bsums);
    scan_mid<<<1, 64, 0, stream>>>(bsums, NB_SCAN, offsets, N);
    scan_out<<<NB_SCAN, 256, 0, stream>>>(counts, N, bsums, offsets);
    scatter_kernel<<<NB_HIST, 256, 0, stream>>>(src, dst, ea, E, offsets, counts, csr);

    // ---- layer 0 (rank-collapsed, fused agg+expand) ----
    agg0x_kernel<<<cdiv(N, 64), 256, 0, stream>>>(
        x, gcoef, Wv0, bv0, We0, Ws0, bs0, (uint2*)H0b, offsets, csr, N);

    // ---- layer 1 ----
    gemm4_kernel<<<cdiv(N, 128), 256, 0, stream>>>(
        H0b, N, wpk,
        bq1, Qb, 128,
        bk1, KV, 256,        // K half of KV row
        bv1, KV + 128, 256,  // V half of KV row
        bs1, S1b, 128);
    agg1_kernel<<<cdiv(N, 4), 256, 0, stream>>>(
        (const uint2*)Qb, KV, We1, (const uint2*)S1b, (uint2*)S1b,
        offsets, csr, N);

    // ---- classifier (fused) ----
    classifier_kernel<<<cdiv(N, 64), 256, 0, stream>>>(
        S1b, N, wpk + 65536, bc1, wpk + 81920, bc2, Wc3, bc3, (float*)d_out);
}